// Round 7
// baseline (70.882 us; speedup 1.0000x reference)
//
#include <hip/hip_runtime.h>

// Problem constants
#define DMODEL 256
#define HEADS 8
#define DHEAD 32
#define NSEQ 2048
#define BATCH 4
#define MTOT (BATCH*NSEQ)   // 8192

typedef __bf16 bf16x8 __attribute__((ext_vector_type(8)));
typedef float f32x4 __attribute__((ext_vector_type(4)));

// scale * log2(e): softmax_e(s/sqrt(32)) == softmax_2(s * CS)
#define CS 0.25507282111989365f

__device__ __forceinline__ unsigned short f2bf(float f) {
    union { float f; unsigned int u; } v; v.f = f;
    unsigned int u = v.u;
    unsigned int r = u + 0x7FFFu + ((u >> 16) & 1u);   // RNE
    return (unsigned short)(r >> 16);
}

__device__ __forceinline__ unsigned pkbf(float a, float b) {
    union { __bf16 h[2]; unsigned u; } t;
    t.h[0] = (__bf16)a; t.h[1] = (__bf16)b;
    return t.u;
}

__device__ __forceinline__ f32x4 mfma16(bf16x8 a, bf16x8 b, f32x4 c) {
    return __builtin_amdgcn_mfma_f32_16x16x32_bf16(a, b, c, 0, 0, 0);
}

#define GLD16(g, l) __builtin_amdgcn_global_load_lds( \
    (const __attribute__((address_space(1))) unsigned int*)(g), \
    (__attribute__((address_space(3))) unsigned int*)(l), 16, 0, 0)

// ---------------------------------------------------------------------------
// prep: x -> bf16, weights -> bf16 transposed Wt[n][k], biases -> concat fp32.
// Blocks >= 3333: Woc = Wo@Wc fold. Block k (0..256), lane n: fp32 dot of
// (k<256 ? Wo row k : bo) with Wc column n. A-row is wave-uniform (s_load),
// Wc reads coalesced. Writes Woct[n][k] bf16 and bocf[n] = .. + bc[n].
// ---------------------------------------------------------------------------
__global__ __launch_bounds__(256) void prep_kernel(
    const float* __restrict__ x,
    const float* __restrict__ Wq, const float* __restrict__ Wk,
    const float* __restrict__ Wv, const float* __restrict__ Wo,
    const float* __restrict__ Wc,
    const float* __restrict__ bq, const float* __restrict__ bk,
    const float* __restrict__ bv, const float* __restrict__ bo,
    const float* __restrict__ bc,
    unsigned short* __restrict__ xbf,   // [8192][256]
    unsigned short* __restrict__ Wt,    // [1280][256]
    float* __restrict__ bcat,           // [1280]
    unsigned short* __restrict__ Woct,  // [256][256] = Woc^T bf16
    float* __restrict__ bocf)           // [256]
{
    if (blockIdx.x >= 3333) {           // Woc / boc fold blocks
        int k = blockIdx.x - 3333;      // 0..256
        int n = threadIdx.x;            // 0..255
        const float* arow = (k < 256) ? (Wo + k * 256) : bo;
        float acc = 0.f;
#pragma unroll 4
        for (int j = 0; j < 256; ++j)
            acc = fmaf(arow[j], Wc[j * 256 + n], acc);
        if (k < 256) Woct[n * 256 + k] = f2bf(acc);
        else         bocf[n] = acc + bc[n];
        return;
    }
    int idx = blockIdx.x * 256 + threadIdx.x;
    const int nx4 = (MTOT * DMODEL) / 4;        // 524288
    if (idx < nx4) {
        float4 v = reinterpret_cast<const float4*>(x)[idx];
        ushort4 o;
        o.x = f2bf(v.x); o.y = f2bf(v.y); o.z = f2bf(v.z); o.w = f2bf(v.w);
        reinterpret_cast<ushort4*>(xbf)[idx] = o;
        return;
    }
    int t = idx - nx4;
    if (t < 1280 * 256) {                        // weight transpose
        int n = t >> 8, k = t & 255;
        const float* Wsrc; int col;
        if (n < 256)       { Wsrc = Wq; col = n; }
        else if (n < 512)  { Wsrc = Wk; col = n - 256; }
        else if (n < 768)  { Wsrc = Wv; col = n - 512; }
        else if (n < 1024) { Wsrc = Wo; col = n - 768; }
        else               { Wsrc = Wc; col = n - 1024; }
        Wt[t] = f2bf(Wsrc[k * 256 + col]);
        return;
    }
    t -= 1280 * 256;
    if (t < 1280) {
        float v;
        if (t < 256)       v = bq[t];
        else if (t < 512)  v = bk[t - 256];
        else if (t < 768)  v = bv[t - 512];
        else if (t < 1024) v = bo[t - 768];
        else               v = bc[t - 1024];
        bcat[t] = v;
    }
}

// ---------------------------------------------------------------------------
// GEMM: out = A @ W + bias, W given as Wt[n][k] bf16, staged in LDS
// (XOR-swizzled 16B blocks via pre-swizzled global_load_lds source).
// Per wave: 32 rows x 64 cols (2x4 acc, 8 MFMA / k-step).
// MODE 0: QKV -> Q (PRE-SCALED by CS), K, Vt
// MODE 2: out fp32 = residual + acc + bias
// ---------------------------------------------------------------------------
template<int MODE, int WM>
__global__ __launch_bounds__(WM * 64) void gemm32(
    const unsigned short* __restrict__ A,
    const unsigned short* __restrict__ Wt,
    const float* __restrict__ bias,
    const float* __restrict__ xres,
    unsigned short* __restrict__ outQ,
    unsigned short* __restrict__ outK,
    unsigned short* __restrict__ outVt,
    float* __restrict__ outF)
{
    __shared__ __align__(16) unsigned short Bl[64 * 256];   // 32 KB
    const int tid = threadIdx.x;
    const int wid = tid >> 6;
    const int lane = tid & 63;
    const int lo = lane & 15, hi = lane >> 4;
    const int m0 = blockIdx.x * (WM * 32) + wid * 32;
    const int n0 = blockIdx.y * 64;

    const int NCALL = 2048 / (WM * 64);
#pragma unroll
    for (int j = 0; j < NCALL; ++j) {
        int chunkbase = (j * WM + wid) * 64;
        int chunk = chunkbase + lane;
        int row = chunk >> 5, Jp = chunk & 31;
        int J = (Jp & 24) | ((Jp ^ row) & 7);
        GLD16(Wt + (n0 + row) * 256 + J * 8, Bl + chunkbase * 8);
    }
    asm volatile("s_waitcnt vmcnt(0)" ::: "memory");
    __syncthreads();

    const unsigned short* arow0 = A + (m0 + lo) * 256 + hi * 8;
    f32x4 acc[2][4] = {};
#pragma unroll
    for (int s = 0; s < 8; ++s) {
        bf16x8 a0 = *reinterpret_cast<const bf16x8*>(arow0 + s * 32);
        bf16x8 a1 = *reinterpret_cast<const bf16x8*>(arow0 + 16 * 256 + s * 32);
        int Jp = ((s >> 1) << 3) | ((((s & 1) << 2) + hi) ^ (lo & 7));
#pragma unroll
        for (int n = 0; n < 4; ++n) {
            bf16x8 b = *reinterpret_cast<const bf16x8*>(
                Bl + (n * 16 + lo) * 256 + Jp * 8);
            acc[0][n] = mfma16(a0, b, acc[0][n]);
            acc[1][n] = mfma16(a1, b, acc[1][n]);
        }
    }
#pragma unroll
    for (int mf = 0; mf < 2; ++mf) {
        const int row_base = m0 + mf * 16 + hi * 4;
#pragma unroll
        for (int n = 0; n < 4; ++n) {
            int gc = n0 + n * 16 + lo;
            float bs = bias[gc];
#pragma unroll
            for (int i = 0; i < 4; ++i) {
                int m = row_base + i;
                float val = acc[mf][n][i] + bs;
                if (MODE == 0) {
                    int b = m >> 11, nn = m & 2047;
                    int which = gc >> 8, hh = (gc >> 5) & 7, dh = gc & 31;
                    if (which == 0)
                        outQ[(((b * 8) + hh) * 2048 + nn) * 32 + dh] = f2bf(val * CS);
                    else if (which == 1)
                        outK[(((b * 8) + hh) * 2048 + nn) * 32 + dh] = f2bf(val);
                    else
                        outVt[(((b * 8) + hh) * 32 + dh) * 2048 + nn] = f2bf(val);
                } else {
                    outF[m * 256 + gc] = xres[m * 256 + gc] + val;
                }
            }
        }
    }
}

// ---------------------------------------------------------------------------
// Flash attention v4: no-max softmax, P in-register (permlane redistribute),
// split-KV (512 threads: waves 0-3 keys [0,1024), waves 4-7 [1024,2048)),
// TRIPLE-buffered K/V with prefetch distance 2 and counted vmcnt(2) —
// loads stay in flight across barriers (T4); buffers rotate via named
// pointers (no runtime-indexed arrays). Partials combined via LDS.
// ---------------------------------------------------------------------------
__global__ __launch_bounds__(512, 6) void attn_kernel(
    const unsigned short* __restrict__ Q,    // [32][2048][32] bf16 (pre-scaled)
    const unsigned short* __restrict__ K,    // [32][2048][32] bf16
    const unsigned short* __restrict__ Vt,   // [32][32][2048] bf16
    unsigned short* __restrict__ ctx)        // [8192][256] bf16 (heads merged)
{
    // [0,24K): K bufs (half,buf 4KB x3 each); [24K,48K): V bufs
    // combine phase reuses first 12KB as [4][64][12] f32
    __shared__ __align__(16) char smem[49152];

    const int tid = threadIdx.x;
    const int wid = tid >> 6;          // 0..7
    const int lane = tid & 63;
    const int lo = lane & 15, hi = lane >> 4;
    const int half = wid >> 2;         // KV half
    const int qw = wid & 3;            // q sub-tile

    // XCD-swizzled decode: bid = 8*(qt + 32*g) + r, bh = g*8+r
    const int bid = blockIdx.x;
    const int bh = ((bid >> 8) << 3) | (bid & 7);
    const int qt = (bid >> 3) & 31;
    const int q0 = qt * 64 + qw * 16;

    const unsigned short* Qb = Q + bh * (NSEQ * 32);
    const unsigned short* Kb = K + bh * (NSEQ * 32);
    const unsigned short* Vb = Vt + bh * (32 * NSEQ);

    bf16x8 qf = *reinterpret_cast<const bf16x8*>(Qb + (q0 + lo) * 32 + hi * 8);

    const int lt = tid & 255;
    const int kbase = half * 1024;
    const unsigned short* ksrc = Kb + (kbase + 2 * (lt >> 3) + ((lt >> 2) & 1)) * 32
                                    + ((lt & 3) ^ ((lt >> 3) & 3)) * 8;
    const unsigned short* vsrc = Vb + (lt >> 3) * NSEQ + kbase
                                    + (((lt & 7) ^ ((lt >> 3) & 7)) * 8);

    char* kb0 = smem + (half * 3 + 0) * 4096;
    char* kb1 = smem + (half * 3 + 1) * 4096;
    char* kb2 = smem + (half * 3 + 2) * 4096;
    char* vb0 = smem + 24576 + (half * 3 + 0) * 4096;
    char* vb1 = smem + 24576 + (half * 3 + 1) * 4096;
    char* vb2 = smem + 24576 + (half * 3 + 2) * 4096;
    const int ldst = lt * 16;          // staging dest byte offset

    f32x4 o0 = {}, o1 = {}, od = {};
    const int prs = lo & 7;
    const int kxor = (hi ^ ((lo >> 1) & 3)) * 8;   // K read swizzle (ushorts)

    union { unsigned u[4]; bf16x8 v; } ones;
    ones.u[0] = 0x3F803F80u; ones.u[1] = 0x3F803F80u;
    ones.u[2] = 0x3F803F80u; ones.u[3] = 0x3F803F80u;

    // prologue: stage tiles 0,1 into bufs 0,1; wait only tile 0 (vmcnt(2))
    GLD16(ksrc,        kb0 + ldst);
    GLD16(vsrc,        vb0 + ldst);
    GLD16(ksrc + 2048, kb1 + ldst);
    GLD16(vsrc + 64,   vb1 + ldst);
    asm volatile("s_waitcnt vmcnt(2)" ::: "memory");
    __builtin_amdgcn_s_barrier();
    __builtin_amdgcn_sched_barrier(0);

    for (int t = 0; t < 16; ++t) {
        if (t < 14) {   // prefetch tile t+2 into the rotating third buffer
            GLD16(ksrc + (t + 2) * 2048, kb2 + ldst);
            GLD16(vsrc + (t + 2) * 64,   vb2 + ldst);
        }
        const unsigned short* Kc = (const unsigned short*)kb0;
        const unsigned short* Vc = (const unsigned short*)vb0;

        __builtin_amdgcn_s_setprio(1);
        // S^T = K Q^T : lane holds S[k=16c+4hi+i][q=q0+lo]
        f32x4 s[4];
#pragma unroll
        for (int c = 0; c < 4; ++c) {
            bf16x8 kf = *reinterpret_cast<const bf16x8*>(
                Kc + (c * 16 + lo) * 32 + kxor);
            f32x4 z = {};
            s[c] = mfma16(kf, qf, z);
        }
        // P = exp2(S); redistribute in-register to PV B-frag layout
#pragma unroll
        for (int kk = 0; kk < 2; ++kk) {
            const f32x4 s0 = s[2 * kk], s1 = s[2 * kk + 1];
            unsigned uA = pkbf(__builtin_amdgcn_exp2f(s0[0]),
                               __builtin_amdgcn_exp2f(s0[1]));
            unsigned uB = pkbf(__builtin_amdgcn_exp2f(s0[2]),
                               __builtin_amdgcn_exp2f(s0[3]));
            unsigned uC = pkbf(__builtin_amdgcn_exp2f(s1[0]),
                               __builtin_amdgcn_exp2f(s1[1]));
            unsigned uD = pkbf(__builtin_amdgcn_exp2f(s1[2]),
                               __builtin_amdgcn_exp2f(s1[3]));
            auto r1 = __builtin_amdgcn_permlane32_swap(uA, uC, false, false);
            auto r2 = __builtin_amdgcn_permlane16_swap(r1[0], r1[1], false, false);
            auto r3 = __builtin_amdgcn_permlane32_swap(uB, uD, false, false);
            auto r4 = __builtin_amdgcn_permlane16_swap(r3[0], r3[1], false, false);
            union { unsigned u[4]; bf16x8 v; } pb;
            pb.u[0] = r2[0]; pb.u[1] = r4[0]; pb.u[2] = r2[1]; pb.u[3] = r4[1];

            int sw = ((4 * kk + hi) ^ prs) << 3;
            bf16x8 a0 = *reinterpret_cast<const bf16x8*>(Vc + lo * 64 + sw);
            bf16x8 a1 = *reinterpret_cast<const bf16x8*>(Vc + (16 + lo) * 64 + sw);
            o0 = mfma16(a0, pb.v, o0);
            o1 = mfma16(a1, pb.v, o1);
            od = mfma16(ones.v, pb.v, od);   // denominator rows
        }
        __builtin_amdgcn_s_setprio(0);

        // counted wait: tile t+1's loads landed; t+2's may stay in flight
        if (t < 14) {
            asm volatile("s_waitcnt vmcnt(2)" ::: "memory");
        } else if (t == 14) {
            asm volatile("s_waitcnt vmcnt(0)" ::: "memory");
        }
        __builtin_amdgcn_s_barrier();
        __builtin_amdgcn_sched_barrier(0);

        // rotate buffers: (0,1,2) <- (1,2,0)
        char* tk = kb0; kb0 = kb1; kb1 = kb2; kb2 = tk;
        char* tv = vb0; vb0 = vb1; vb1 = vb2; vb2 = tv;
    }

    // combine halves: pure addition (no-max softmax partials)
    float* comb = (float*)smem;                 // [4][64][12]
    const int cidx = (qw * 64 + lane) * 12;
    __syncthreads();
    if (wid >= 4) {
        *reinterpret_cast<f32x4*>(comb + cidx)     = o0;
        *reinterpret_cast<f32x4*>(comb + cidx + 4) = o1;
        comb[cidx + 8] = od[0];
    }
    __syncthreads();
    if (wid < 4) {
        f32x4 p0 = *reinterpret_cast<const f32x4*>(comb + cidx);
        f32x4 p1 = *reinterpret_cast<const f32x4*>(comb + cidx + 4);
        float dsum = od[0] + comb[cidx + 8];
        o0 += p0; o1 += p1;
        float inv = 1.0f / dsum;

        const int b = bh >> 3, h = bh & 7;
        unsigned short* dst = ctx + (size_t)((b * 2048 + q0 + lo)) * 256 + h * 32;
        ushort4 w0, w1;
        w0.x = f2bf(o0[0] * inv); w0.y = f2bf(o0[1] * inv);
        w0.z = f2bf(o0[2] * inv); w0.w = f2bf(o0[3] * inv);
        w1.x = f2bf(o1[0] * inv); w1.y = f2bf(o1[1] * inv);
        w1.z = f2bf(o1[2] * inv); w1.w = f2bf(o1[3] * inv);
        *reinterpret_cast<ushort4*>(dst + hi * 4)      = w0;
        *reinterpret_cast<ushort4*>(dst + 16 + hi * 4) = w1;
    }
}

// ---------------------------------------------------------------------------
extern "C" void kernel_launch(void* const* d_in, const int* in_sizes, int n_in,
                              void* d_out, int out_size, void* d_ws, size_t ws_size,
                              hipStream_t stream) {
    const float* x  = (const float*)d_in[0];
    const float* Wq = (const float*)d_in[1];
    const float* bq = (const float*)d_in[2];
    const float* Wk = (const float*)d_in[3];
    const float* bk = (const float*)d_in[4];
    const float* Wv = (const float*)d_in[5];
    const float* bv = (const float*)d_in[6];
    const float* Wo = (const float*)d_in[7];
    const float* bo = (const float*)d_in[8];
    const float* Wc = (const float*)d_in[9];
    const float* bc = (const float*)d_in[10];
    float* out = (float*)d_out;

    char* p = (char*)d_ws;
    unsigned short* xbf  = (unsigned short*)p;  p += (size_t)MTOT * DMODEL * 2;   // 4 MB
    unsigned short* Wt   = (unsigned short*)p;  p += (size_t)1280 * 256 * 2;      // 640 KB
    float* bcat          = (float*)p;           p += (size_t)1280 * 4;            // 5 KB
    unsigned short* Qw   = (unsigned short*)p;  p += (size_t)32 * 2048 * 32 * 2;  // 4 MB
    unsigned short* Kw   = (unsigned short*)p;  p += (size_t)32 * 2048 * 32 * 2;  // 4 MB
    unsigned short* Vtw  = (unsigned short*)p;  p += (size_t)32 * 32 * 2048 * 2;  // 4 MB
    unsigned short* ctx  = (unsigned short*)p;  p += (size_t)MTOT * DMODEL * 2;   // 4 MB
    unsigned short* Woct = (unsigned short*)p;  p += (size_t)256 * 256 * 2;       // 128 KB
    float* bocf          = (float*)p;           p += (size_t)256 * 4;             // 1 KB

    // prep: 3333 blocks main work + 257 blocks Woc/boc fold
    prep_kernel<<<3590, 256, 0, stream>>>(x, Wq, Wk, Wv, Wo, Wc,
                                          bq, bk, bv, bo, bc,
                                          xbf, Wt, bcat, Woct, bocf);
    // QKV projection
    gemm32<0, 4><<<dim3(64, 12), 256, 0, stream>>>(xbf, Wt, bcat, nullptr,
                                                   Qw, Kw, Vtw, nullptr);
    // attention
    attn_kernel<<<1024, 512, 0, stream>>>(Qw, Kw, Vtw, ctx);
    // fused output+context projection + residual: out = x + ctx@Woc + boc
    gemm32<2, 4><<<dim3(64, 4), 256, 0, stream>>>(ctx, Woct, bocf,
                                                  x, nullptr, nullptr, nullptr, out);
}

// Round 8
// 62.796 us; speedup vs baseline: 1.1288x; 1.1288x over previous
//
#include <hip/hip_runtime.h>

// Problem constants
#define DMODEL 256
#define HEADS 8
#define DHEAD 32
#define NSEQ 2048
#define BATCH 4
#define MTOT (BATCH*NSEQ)   // 8192

typedef __bf16 bf16x8 __attribute__((ext_vector_type(8)));
typedef float f32x4 __attribute__((ext_vector_type(4)));

// scale * log2(e): softmax_e(s/sqrt(32)) == softmax_2(s * CS)
#define CS 0.25507282111989365f

__device__ __forceinline__ unsigned short f2bf(float f) {
    union { float f; unsigned int u; } v; v.f = f;
    unsigned int u = v.u;
    unsigned int r = u + 0x7FFFu + ((u >> 16) & 1u);   // RNE
    return (unsigned short)(r >> 16);
}

__device__ __forceinline__ unsigned pkbf(float a, float b) {
    union { __bf16 h[2]; unsigned u; } t;
    t.h[0] = (__bf16)a; t.h[1] = (__bf16)b;
    return t.u;
}

__device__ __forceinline__ f32x4 mfma16(bf16x8 a, bf16x8 b, f32x4 c) {
    return __builtin_amdgcn_mfma_f32_16x16x32_bf16(a, b, c, 0, 0, 0);
}

#define GLD16(g, l) __builtin_amdgcn_global_load_lds( \
    (const __attribute__((address_space(1))) unsigned int*)(g), \
    (__attribute__((address_space(3))) unsigned int*)(l), 16, 0, 0)

// ---------------------------------------------------------------------------
// prep: blocks 0..256 = Woc fold (runs FIRST, overlapped, 4-acc ILP);
// blocks 257+ : x->bf16, weight transpose Wt[n][k], bias concat.
// ---------------------------------------------------------------------------
__global__ __launch_bounds__(256) void prep_kernel(
    const float* __restrict__ x,
    const float* __restrict__ Wq, const float* __restrict__ Wk,
    const float* __restrict__ Wv, const float* __restrict__ Wo,
    const float* __restrict__ Wc,
    const float* __restrict__ bq, const float* __restrict__ bk,
    const float* __restrict__ bv, const float* __restrict__ bo,
    const float* __restrict__ bc,
    unsigned short* __restrict__ xbf,   // [8192][256]
    unsigned short* __restrict__ Wt,    // [1280][256]
    float* __restrict__ bcat,           // [1280]
    unsigned short* __restrict__ Woct,  // [256][256] = Woc^T bf16
    float* __restrict__ bocf)           // [256]
{
    if (blockIdx.x < 257) {             // Woc / boc fold
        int k = blockIdx.x;             // 0..256
        int n = threadIdx.x;            // 0..255
        const float* arow = (k < 256) ? (Wo + k * 256) : bo;
        float a0 = 0.f, a1 = 0.f, a2 = 0.f, a3 = 0.f;
#pragma unroll 4
        for (int j = 0; j < 256; j += 4) {
            a0 = fmaf(arow[j],     Wc[j * 256 + n],       a0);
            a1 = fmaf(arow[j + 1], Wc[(j + 1) * 256 + n], a1);
            a2 = fmaf(arow[j + 2], Wc[(j + 2) * 256 + n], a2);
            a3 = fmaf(arow[j + 3], Wc[(j + 3) * 256 + n], a3);
        }
        float acc = (a0 + a1) + (a2 + a3);
        if (k < 256) Woct[n * 256 + k] = f2bf(acc);
        else         bocf[n] = acc + bc[n];
        return;
    }
    int idx = (blockIdx.x - 257) * 256 + threadIdx.x;
    const int nx4 = (MTOT * DMODEL) / 4;        // 524288
    if (idx < nx4) {
        float4 v = reinterpret_cast<const float4*>(x)[idx];
        ushort4 o;
        o.x = f2bf(v.x); o.y = f2bf(v.y); o.z = f2bf(v.z); o.w = f2bf(v.w);
        reinterpret_cast<ushort4*>(xbf)[idx] = o;
        return;
    }
    int t = idx - nx4;
    if (t < 1280 * 256) {                        // weight transpose
        int n = t >> 8, k = t & 255;
        const float* Wsrc; int col;
        if (n < 256)       { Wsrc = Wq; col = n; }
        else if (n < 512)  { Wsrc = Wk; col = n - 256; }
        else if (n < 768)  { Wsrc = Wv; col = n - 512; }
        else if (n < 1024) { Wsrc = Wo; col = n - 768; }
        else               { Wsrc = Wc; col = n - 1024; }
        Wt[t] = f2bf(Wsrc[k * 256 + col]);
        return;
    }
    t -= 1280 * 256;
    if (t < 1280) {
        float v;
        if (t < 256)       v = bq[t];
        else if (t < 512)  v = bk[t - 256];
        else if (t < 768)  v = bv[t - 512];
        else if (t < 1024) v = bo[t - 768];
        else               v = bc[t - 1024];
        bcat[t] = v;
    }
}

// ---------------------------------------------------------------------------
// GEMM: out = A @ W + bias, Wt[n][k] bf16 staged in LDS (XOR-swizzled 16B
// blocks via pre-swizzled global_load_lds source). 32 rows x 64 cols / wave.
// MODE 0: QKV. Epilogue bounces through LDS so ALL global stores are b128:
//   type 0/1 (Q/K): LDS [128 m][72 gc-pad] -> row chunks; Q pre-scaled by CS.
//   type 2 (V): LDS [64 gc][136 m-pad] (transposed) -> Vt row chunks.
// MODE 2: out fp32 = residual + acc + bias (direct, already coalesced).
// ---------------------------------------------------------------------------
template<int MODE, int WM>
__global__ __launch_bounds__(WM * 64) void gemm32(
    const unsigned short* __restrict__ A,
    const unsigned short* __restrict__ Wt,
    const float* __restrict__ bias,
    const float* __restrict__ xres,
    unsigned short* __restrict__ outQ,
    unsigned short* __restrict__ outK,
    unsigned short* __restrict__ outVt,
    float* __restrict__ outF)
{
    __shared__ __align__(16) unsigned short Bl[64 * 256];   // 32 KB
    const int tid = threadIdx.x;
    const int wid = tid >> 6;
    const int lane = tid & 63;
    const int lo = lane & 15, hi = lane >> 4;
    const int m0 = blockIdx.x * (WM * 32) + wid * 32;
    const int n0 = blockIdx.y * 64;

    const int NCALL = 2048 / (WM * 64);
#pragma unroll
    for (int j = 0; j < NCALL; ++j) {
        int chunkbase = (j * WM + wid) * 64;
        int chunk = chunkbase + lane;
        int row = chunk >> 5, Jp = chunk & 31;
        int J = (Jp & 24) | ((Jp ^ row) & 7);
        GLD16(Wt + (n0 + row) * 256 + J * 8, Bl + chunkbase * 8);
    }
    asm volatile("s_waitcnt vmcnt(0)" ::: "memory");
    __syncthreads();

    const unsigned short* arow0 = A + (m0 + lo) * 256 + hi * 8;
    f32x4 acc[2][4] = {};
#pragma unroll
    for (int s = 0; s < 8; ++s) {
        bf16x8 a0 = *reinterpret_cast<const bf16x8*>(arow0 + s * 32);
        bf16x8 a1 = *reinterpret_cast<const bf16x8*>(arow0 + 16 * 256 + s * 32);
        int Jp = ((s >> 1) << 3) | ((((s & 1) << 2) + hi) ^ (lo & 7));
#pragma unroll
        for (int n = 0; n < 4; ++n) {
            bf16x8 b = *reinterpret_cast<const bf16x8*>(
                Bl + (n * 16 + lo) * 256 + Jp * 8);
            acc[0][n] = mfma16(a0, b, acc[0][n]);
            acc[1][n] = mfma16(a1, b, acc[1][n]);
        }
    }

    if (MODE == 2) {
#pragma unroll
        for (int mf = 0; mf < 2; ++mf) {
            const int row_base = m0 + mf * 16 + hi * 4;
#pragma unroll
            for (int n = 0; n < 4; ++n) {
                int gc = n0 + n * 16 + lo;
                float bs = bias[gc];
#pragma unroll
                for (int i = 0; i < 4; ++i)
                    outF[(row_base + i) * 256 + gc] =
                        xres[(row_base + i) * 256 + gc] + acc[mf][n][i] + bs;
            }
        }
        return;
    }

    // MODE 0: LDS-bounce epilogue
    const int type = blockIdx.y >> 2;     // 0:Q 1:K 2:V (uniform per block)
    const int m0b = blockIdx.x * 128;
    unsigned short* Lb = Bl;              // reuse W tile (done with it)
    __syncthreads();
    if (type < 2) {                       // [128][72]
#pragma unroll
        for (int mf = 0; mf < 2; ++mf)
#pragma unroll
        for (int n = 0; n < 4; ++n) {
            float bs = bias[n0 + n * 16 + lo];
#pragma unroll
            for (int i = 0; i < 4; ++i) {
                float val = acc[mf][n][i] + bs;
                if (type == 0) val *= CS;
                Lb[(wid * 32 + mf * 16 + hi * 4 + i) * 72 + n * 16 + lo] = f2bf(val);
            }
        }
    } else {                              // transposed [64][136]
#pragma unroll
        for (int mf = 0; mf < 2; ++mf)
#pragma unroll
        for (int n = 0; n < 4; ++n) {
            float bs = bias[n0 + n * 16 + lo];
            uint2 pk;
            pk.x = pkbf(acc[mf][n][0] + bs, acc[mf][n][1] + bs);
            pk.y = pkbf(acc[mf][n][2] + bs, acc[mf][n][3] + bs);
            *reinterpret_cast<uint2*>(
                Lb + (n * 16 + lo) * 136 + wid * 32 + mf * 16 + hi * 4) = pk;
        }
    }
    __syncthreads();
    if (type < 2) {
        unsigned short* outP = (type == 0) ? outQ : outK;
#pragma unroll
        for (int r = 0; r < 4; ++r) {
            int cid = r * 256 + tid;
            int m_l = cid >> 3, seg = cid & 7;
            bf16x8 chunk = *reinterpret_cast<const bf16x8*>(Lb + m_l * 72 + seg * 8);
            int m = m0b + m_l, gc = n0 + seg * 8;
            int b = m >> 11, nn = m & 2047, hh = (gc >> 5) & 7, dh = gc & 31;
            *reinterpret_cast<bf16x8*>(
                outP + (((b * 8) + hh) * 2048 + nn) * 32 + dh) = chunk;
        }
    } else {
#pragma unroll
        for (int r = 0; r < 4; ++r) {
            int cid = r * 256 + tid;
            int gcl = cid >> 4, seg = cid & 15;
            bf16x8 chunk = *reinterpret_cast<const bf16x8*>(Lb + gcl * 136 + seg * 8);
            int gc = n0 + gcl, m = m0b + seg * 8;
            int b = m >> 11, nn = m & 2047, hh = (gc >> 5) & 7, dh = gc & 31;
            *reinterpret_cast<bf16x8*>(
                outVt + (((b * 8) + hh) * 32 + dh) * 2048 + nn) = chunk;
        }
    }
}

// ---------------------------------------------------------------------------
// Flash attention v5: 32 q-rows per wave (two 16-row groups A/B sharing every
// K/V fragment -> LDS bytes per q*k halved), KVBLK=128, split-KV halves
// (8 waves = 4 qw x 2 half), double-buffered 64KB LDS, no-max softmax,
// P in-register via permlane, denom via ones-MFMA. Combine halves via LDS.
// ---------------------------------------------------------------------------
__global__ __launch_bounds__(512, 4) void attn_kernel(
    const unsigned short* __restrict__ Q,    // [32][2048][32] bf16 (pre-scaled)
    const unsigned short* __restrict__ K,    // [32][2048][32] bf16
    const unsigned short* __restrict__ Vt,   // [32][32][2048] bf16
    unsigned short* __restrict__ ctx)        // [8192][256] bf16 (heads merged)
{
    // K region: [half][buf][sub] = half*16384 + buf*8192 + sub*4096
    // V region: same + 32768. Combine reuses [0,18432).
    __shared__ __align__(16) char smem[65536];

    const int tid = threadIdx.x;
    const int wid = tid >> 6;          // 0..7
    const int lane = tid & 63;
    const int lo = lane & 15, hi = lane >> 4;
    const int half = wid >> 2;
    const int qw = wid & 3;

    // XCD swizzle: 512 blocks; bid = 8*(qt + 16*g) + r ; bh = g*8+r
    const int bid = blockIdx.x;
    const int bh = ((bid >> 7) << 3) | (bid & 7);
    const int qt = (bid >> 3) & 15;
    const int q0 = qt * 128 + qw * 32;

    const unsigned short* Qb = Q + bh * (NSEQ * 32);
    const unsigned short* Kb = K + bh * (NSEQ * 32);
    const unsigned short* Vb = Vt + bh * (32 * NSEQ);

    bf16x8 qfA = *reinterpret_cast<const bf16x8*>(Qb + (q0 + lo) * 32 + hi * 8);
    bf16x8 qfB = *reinterpret_cast<const bf16x8*>(Qb + (q0 + 16 + lo) * 32 + hi * 8);

    // staging (256 threads per half, 4 GLD16 per thread per 128-key tile)
    const int lt = tid & 255;
    const int kb0 = half * 1024;       // key base of this half
    const unsigned short* ksrc0 = Kb + (kb0 + 2 * (lt >> 3) + ((lt >> 2) & 1)) * 32
                                     + ((lt & 3) ^ ((lt >> 3) & 3)) * 8;
    const unsigned short* ksrc1 = ksrc0 + 64 * 32;
    const unsigned short* vsrc0 = Vb + (lt >> 3) * NSEQ + kb0
                                     + ((lt & 7) ^ ((lt >> 3) & 7)) * 8;
    const unsigned short* vsrc1 = vsrc0 + 64;
    char* kdst = smem + half * 16384 + lt * 16;
    char* vdst = smem + 32768 + half * 16384 + lt * 16;

    f32x4 o0A = {}, o1A = {}, odA = {};
    f32x4 o0B = {}, o1B = {}, odB = {};
    const f32x4 z = {};
    const int prs = lo & 7;
    const int kxor = (hi ^ ((lo >> 1) & 3)) * 8;

    union { unsigned u[4]; bf16x8 v; } ones;
    ones.u[0] = 0x3F803F80u; ones.u[1] = 0x3F803F80u;
    ones.u[2] = 0x3F803F80u; ones.u[3] = 0x3F803F80u;

#define STAGE_T(tt, buf) do { \
    GLD16(ksrc0 + (tt) * 4096, kdst + (buf) * 8192); \
    GLD16(ksrc1 + (tt) * 4096, kdst + (buf) * 8192 + 4096); \
    GLD16(vsrc0 + (tt) * 128,  vdst + (buf) * 8192); \
    GLD16(vsrc1 + (tt) * 128,  vdst + (buf) * 8192 + 4096); \
} while (0)

    STAGE_T(0, 0);
    asm volatile("s_waitcnt vmcnt(0)" ::: "memory");
    __builtin_amdgcn_s_barrier();
    __builtin_amdgcn_sched_barrier(0);

    int cur = 0;
    for (int t = 0; t < 8; ++t) {
        if (t < 7) STAGE_T(t + 1, cur ^ 1);
        const unsigned short* Kc =
            (const unsigned short*)(smem + half * 16384 + cur * 8192);
        const unsigned short* Vc =
            (const unsigned short*)(smem + 32768 + half * 16384 + cur * 8192);

        __builtin_amdgcn_s_setprio(1);
#pragma unroll
        for (int h2 = 0; h2 < 2; ++h2) {     // 64-key sub-tiles
            const unsigned short* Kh = Kc + h2 * 2048;
            const unsigned short* Vh = Vc + h2 * 2048;
            f32x4 sA[4], sB[4];
#pragma unroll
            for (int c = 0; c < 4; ++c) {
                bf16x8 kf = *reinterpret_cast<const bf16x8*>(
                    Kh + (c * 16 + lo) * 32 + kxor);
                sA[c] = mfma16(kf, qfA, z);
                sB[c] = mfma16(kf, qfB, z);
            }
#pragma unroll
            for (int kk = 0; kk < 2; ++kk) {
                // group A pack
                unsigned uA = pkbf(__builtin_amdgcn_exp2f(sA[2 * kk][0]),
                                   __builtin_amdgcn_exp2f(sA[2 * kk][1]));
                unsigned uB = pkbf(__builtin_amdgcn_exp2f(sA[2 * kk][2]),
                                   __builtin_amdgcn_exp2f(sA[2 * kk][3]));
                unsigned uC = pkbf(__builtin_amdgcn_exp2f(sA[2 * kk + 1][0]),
                                   __builtin_amdgcn_exp2f(sA[2 * kk + 1][1]));
                unsigned uD = pkbf(__builtin_amdgcn_exp2f(sA[2 * kk + 1][2]),
                                   __builtin_amdgcn_exp2f(sA[2 * kk + 1][3]));
                auto r1 = __builtin_amdgcn_permlane32_swap(uA, uC, false, false);
                auto r2 = __builtin_amdgcn_permlane16_swap(r1[0], r1[1], false, false);
                auto r3 = __builtin_amdgcn_permlane32_swap(uB, uD, false, false);
                auto r4 = __builtin_amdgcn_permlane16_swap(r3[0], r3[1], false, false);
                union { unsigned u[4]; bf16x8 v; } pbA;
                pbA.u[0] = r2[0]; pbA.u[1] = r4[0]; pbA.u[2] = r2[1]; pbA.u[3] = r4[1];
                // group B pack
                unsigned wA = pkbf(__builtin_amdgcn_exp2f(sB[2 * kk][0]),
                                   __builtin_amdgcn_exp2f(sB[2 * kk][1]));
                unsigned wB = pkbf(__builtin_amdgcn_exp2f(sB[2 * kk][2]),
                                   __builtin_amdgcn_exp2f(sB[2 * kk][3]));
                unsigned wC = pkbf(__builtin_amdgcn_exp2f(sB[2 * kk + 1][0]),
                                   __builtin_amdgcn_exp2f(sB[2 * kk + 1][1]));
                unsigned wD = pkbf(__builtin_amdgcn_exp2f(sB[2 * kk + 1][2]),
                                   __builtin_amdgcn_exp2f(sB[2 * kk + 1][3]));
                auto t1 = __builtin_amdgcn_permlane32_swap(wA, wC, false, false);
                auto t2 = __builtin_amdgcn_permlane16_swap(t1[0], t1[1], false, false);
                auto t3 = __builtin_amdgcn_permlane32_swap(wB, wD, false, false);
                auto t4 = __builtin_amdgcn_permlane16_swap(t3[0], t3[1], false, false);
                union { unsigned u[4]; bf16x8 v; } pbB;
                pbB.u[0] = t2[0]; pbB.u[1] = t4[0]; pbB.u[2] = t2[1]; pbB.u[3] = t4[1];

                int sw = ((4 * kk + hi) ^ prs) * 8;
                bf16x8 a0 = *reinterpret_cast<const bf16x8*>(Vh + lo * 64 + sw);
                bf16x8 a1 = *reinterpret_cast<const bf16x8*>(Vh + (16 + lo) * 64 + sw);
                o0A = mfma16(a0, pbA.v, o0A);
                o1A = mfma16(a1, pbA.v, o1A);
                odA = mfma16(ones.v, pbA.v, odA);
                o0B = mfma16(a0, pbB.v, o0B);
                o1B = mfma16(a1, pbB.v, o1B);
                odB = mfma16(ones.v, pbB.v, odB);
            }
        }
        __builtin_amdgcn_s_setprio(0);

        if (t < 7) {
            asm volatile("s_waitcnt vmcnt(0)" ::: "memory");
            __builtin_amdgcn_s_barrier();
            __builtin_amdgcn_sched_barrier(0);
            cur ^= 1;
        }
    }

    // combine halves (pure addition; no-max softmax partials)
    float* comb = (float*)smem;                 // [4][64][18]
    const int cidx = (qw * 64 + lane) * 18;
    __syncthreads();
    if (half) {
        *reinterpret_cast<f32x4*>(comb + cidx)      = o0A;
        *reinterpret_cast<f32x4*>(comb + cidx + 4)  = o1A;
        comb[cidx + 8] = odA[0];
        *reinterpret_cast<f32x4*>(comb + cidx + 9)  = o0B;
        *reinterpret_cast<f32x4*>(comb + cidx + 13) = o1B;
        comb[cidx + 17] = odB[0];
    }
    __syncthreads();
    if (!half) {
        o0A += *reinterpret_cast<const f32x4*>(comb + cidx);
        o1A += *reinterpret_cast<const f32x4*>(comb + cidx + 4);
        float invA = 1.0f / (odA[0] + comb[cidx + 8]);
        o0B += *reinterpret_cast<const f32x4*>(comb + cidx + 9);
        o1B += *reinterpret_cast<const f32x4*>(comb + cidx + 13);
        float invB = 1.0f / (odB[0] + comb[cidx + 17]);

        const int b = bh >> 3, h = bh & 7;
        unsigned short* dstA = ctx + (size_t)((b * 2048 + q0 + lo)) * 256 + h * 32;
        unsigned short* dstB = dstA + 16 * 256;
        ushort4 w0, w1;
        w0.x = f2bf(o0A[0] * invA); w0.y = f2bf(o0A[1] * invA);
        w0.z = f2bf(o0A[2] * invA); w0.w = f2bf(o0A[3] * invA);
        w1.x = f2bf(o1A[0] * invA); w1.y = f2bf(o1A[1] * invA);
        w1.z = f2bf(o1A[2] * invA); w1.w = f2bf(o1A[3] * invA);
        *reinterpret_cast<ushort4*>(dstA + hi * 4)      = w0;
        *reinterpret_cast<ushort4*>(dstA + 16 + hi * 4) = w1;
        w0.x = f2bf(o0B[0] * invB); w0.y = f2bf(o0B[1] * invB);
        w0.z = f2bf(o0B[2] * invB); w0.w = f2bf(o0B[3] * invB);
        w1.x = f2bf(o1B[0] * invB); w1.y = f2bf(o1B[1] * invB);
        w1.z = f2bf(o1B[2] * invB); w1.w = f2bf(o1B[3] * invB);
        *reinterpret_cast<ushort4*>(dstB + hi * 4)      = w0;
        *reinterpret_cast<ushort4*>(dstB + 16 + hi * 4) = w1;
    }
#undef STAGE_T
}

// ---------------------------------------------------------------------------
extern "C" void kernel_launch(void* const* d_in, const int* in_sizes, int n_in,
                              void* d_out, int out_size, void* d_ws, size_t ws_size,
                              hipStream_t stream) {
    const float* x  = (const float*)d_in[0];
    const float* Wq = (const float*)d_in[1];
    const float* bq = (const float*)d_in[2];
    const float* Wk = (const float*)d_in[3];
    const float* bk = (const float*)d_in[4];
    const float* Wv = (const float*)d_in[5];
    const float* bv = (const float*)d_in[6];
    const float* Wo = (const float*)d_in[7];
    const float* bo = (const float*)d_in[8];
    const float* Wc = (const float*)d_in[9];
    const float* bc = (const float*)d_in[10];
    float* out = (float*)d_out;

    char* p = (char*)d_ws;
    unsigned short* xbf  = (unsigned short*)p;  p += (size_t)MTOT * DMODEL * 2;   // 4 MB
    unsigned short* Wt   = (unsigned short*)p;  p += (size_t)1280 * 256 * 2;      // 640 KB
    float* bcat          = (float*)p;           p += (size_t)1280 * 4;            // 5 KB
    unsigned short* Qw   = (unsigned short*)p;  p += (size_t)32 * 2048 * 32 * 2;  // 4 MB
    unsigned short* Kw   = (unsigned short*)p;  p += (size_t)32 * 2048 * 32 * 2;  // 4 MB
    unsigned short* Vtw  = (unsigned short*)p;  p += (size_t)32 * 32 * 2048 * 2;  // 4 MB
    unsigned short* ctx  = (unsigned short*)p;  p += (size_t)MTOT * DMODEL * 2;   // 4 MB
    unsigned short* Woct = (unsigned short*)p;  p += (size_t)256 * 256 * 2;       // 128 KB
    float* bocf          = (float*)p;           p += (size_t)256 * 4;             // 1 KB

    // prep: 257 fold blocks FIRST + 3333 bulk blocks
    prep_kernel<<<3590, 256, 0, stream>>>(x, Wq, Wk, Wv, Wo, Wc,
                                          bq, bk, bv, bo, bc,
                                          xbf, Wt, bcat, Woct, bocf);
    // QKV projection (coalesced LDS-bounce epilogue)
    gemm32<0, 4><<<dim3(64, 12), 256, 0, stream>>>(xbf, Wt, bcat, nullptr,
                                                   Qw, Kw, Vtw, nullptr);
    // attention
    attn_kernel<<<512, 512, 0, stream>>>(Qw, Kw, Vtw, ctx);
    // fused output+context projection + residual: out = x + ctx@Woc + boc
    gemm32<2, 4><<<dim3(64, 4), 256, 0, stream>>>(ctx, Woct, bocf,
                                                  x, nullptr, nullptr, nullptr, out);
}